// Round 14
// baseline (678.013 us; speedup 1.0000x reference)
//
#include <hip/hip_runtime.h>
#include <hip/hip_fp16.h>
#include <stdint.h>
#include <stddef.h>

typedef float f32x4 __attribute__((ext_vector_type(4)));
typedef int   i32x8 __attribute__((ext_vector_type(8)));

#define GLOBAL_AS __attribute__((address_space(1)))
#define LDS_AS    __attribute__((address_space(3)))

__device__ __forceinline__ void gload_lds16(const void* g, void* l) {
    __builtin_amdgcn_global_load_lds((const GLOBAL_AS void*)g,
                                     (LDS_AS void*)l, 16, 0, 0);
}

// ---------------- fused amax (x -> scal[0], w -> scal[1]) ----------------
__global__ void amax2_kernel(const float* __restrict__ x, size_t nx4,
                             const float* __restrict__ w, size_t nw4,
                             float* __restrict__ scal, int xblocks, int wblocks) {
    int b = blockIdx.x;
    const float4* p4; size_t n4; float* out; int nb; int bb;
    if (b < xblocks) { p4 = (const float4*)x; n4 = nx4; out = scal;     nb = xblocks; bb = b; }
    else             { p4 = (const float4*)w; n4 = nw4; out = scal + 1; nb = wblocks; bb = b - xblocks; }
    float m = 0.f;
    for (size_t i = (size_t)bb * blockDim.x + threadIdx.x; i < n4;
         i += (size_t)nb * blockDim.x) {
        float4 v = p4[i];
        m = fmaxf(m, fmaxf(fmaxf(fabsf(v.x), fabsf(v.y)),
                           fmaxf(fabsf(v.z), fabsf(v.w))));
    }
    #pragma unroll
    for (int off = 32; off > 0; off >>= 1)
        m = fmaxf(m, __shfl_down(m, off, 64));
    __shared__ float sm[4];
    int wid = threadIdx.x >> 6;
    if ((threadIdx.x & 63) == 0) sm[wid] = m;
    __syncthreads();
    if (threadIdx.x == 0) {
        m = fmaxf(fmaxf(sm[0], sm[1]), fmaxf(sm[2], sm[3]));
        atomicMax((unsigned int*)out, __float_as_uint(m));
    }
}

// ---------------- fused fp8 e4m3 quantization (16 elems/thread) ----------------
__global__ void quant2_kernel(const float* __restrict__ x, const float* __restrict__ w,
                              const float* __restrict__ scal,
                              uint32_t* __restrict__ qx, uint32_t* __restrict__ qw,
                              int xblocks) {
    int b = blockIdx.x;
    const float* src; uint32_t* dst; float sc; size_t i;
    if (b < xblocks) { src = x; dst = qx; sc = 448.f / fmaxf(scal[0], 1e-12f);
                       i = (size_t)b * blockDim.x + threadIdx.x; }
    else             { src = w; dst = qw; sc = 448.f / fmaxf(scal[1], 1e-12f);
                       i = (size_t)(b - xblocks) * blockDim.x + threadIdx.x; }
    const float4* s4 = (const float4*)src + i * 4;
    uint32_t r[4];
    #pragma unroll
    for (int j = 0; j < 4; ++j) {
        float4 v = s4[j];
        uint32_t u = __builtin_amdgcn_cvt_pk_fp8_f32(v.x * sc, v.y * sc, 0u, false);
        u = __builtin_amdgcn_cvt_pk_fp8_f32(v.z * sc, v.w * sc, u, true);
        r[j] = u;
    }
    uint4 out; out.x = r[0]; out.y = r[1]; out.z = r[2]; out.w = r[3];
    *(uint4*)(dst + i * 4) = out;
}

// ------- MX-fp8 GEMM, B streamed global->reg (AITER s02 style) -------
// A: LDS double-buffered (swizzled, gload_lds).  B: wave-private frags loaded
// straight from L2 with counted vmcnt(8) prefetch that stays in flight across
// the single per-tile barrier.  Halves ds_read + gload_lds vs r3.
#define BM 128
#define BN 128
#define BKB 128

__global__ __launch_bounds__(256) void gemm_mxfp8_bs(
    const uint8_t* __restrict__ Aq,   // [M][K] fp8
    const uint8_t* __restrict__ Bq,   // [N][K] fp8
    const float* __restrict__ scal,   // {amax_x, amax_w}
    const float* __restrict__ bias,   // [N] f32 holding fp16-exact values
    float* __restrict__ C,            // [M][N] f32 (fp16-rounded values)
    int M, int N, int K)
{
    __shared__ __align__(16) uint8_t As[2][BM * BKB];   // 32 KB, double-buffered

    const int tid  = threadIdx.x;
    const int wid  = tid >> 6;
    const int lane = tid & 63;
    const int wm = wid >> 1, wn = wid & 1;   // 2x2 waves, 64x64 each
    const int bn = blockIdx.x, bm = blockIdx.y;
    const int r16 = lane & 15, hi = lane >> 4;

    // ---- A staging (pre-swizzled global source, as r3) ----
    const int srow  = wid * 8 + (lane >> 3);
    const int schunk = ((lane & 7) ^ (lane >> 3)) << 4;
    const uint8_t* Abase = Aq + (size_t)(bm * BM + srow) * K + schunk;

    // ---- A fragment-read swizzle ----
    const int swz = r16 & 7;
    const int u0 = ((hi * 2)     ^ swz) << 4;
    const int u1 = ((hi * 2 + 1) ^ swz) << 4;

    // ---- B direct row pointers: lane (r16,hi) holds k in [hi*32, hi*32+32) ----
    const uint8_t* Brow0 = Bq + (size_t)(bn * BN + wn * 64 + r16) * K + hi * 32;
    const uint8_t* Brow1 = Brow0 + (size_t)16 * K;
    const uint8_t* Brow2 = Brow0 + (size_t)32 * K;
    const uint8_t* Brow3 = Brow0 + (size_t)48 * K;

#define STAGE_A(bufi, t)                                                          \
  { _Pragma("unroll") for (int rho_ = 0; rho_ < 4; ++rho_)                        \
      gload_lds16(Abase + (size_t)rho_ * 32 * K + (t) * BKB,                      \
                  As[bufi] + rho_ * 4096 + wid * 1024); }

#define BLOADS(B0, B1, B2, B3, koff)                                              \
  { ((int4*)&(B0))[0] = *(const int4*)(Brow0 + (koff));                           \
    ((int4*)&(B0))[1] = *(const int4*)(Brow0 + (koff) + 16);                      \
    ((int4*)&(B1))[0] = *(const int4*)(Brow1 + (koff));                           \
    ((int4*)&(B1))[1] = *(const int4*)(Brow1 + (koff) + 16);                      \
    ((int4*)&(B2))[0] = *(const int4*)(Brow2 + (koff));                           \
    ((int4*)&(B2))[1] = *(const int4*)(Brow2 + (koff) + 16);                      \
    ((int4*)&(B3))[0] = *(const int4*)(Brow3 + (koff));                           \
    ((int4*)&(B3))[1] = *(const int4*)(Brow3 + (koff) + 16); }

#define LDA2(bufc, q0, q1)                                                        \
  { const uint8_t* p0_ = As[bufc] + (wm * 64 + (q0) * 16 + r16) * BKB;            \
    ((int4*)&a0)[0] = *(const int4*)(p0_ + u0);                                   \
    ((int4*)&a0)[1] = *(const int4*)(p0_ + u1);                                   \
    const uint8_t* p1_ = As[bufc] + (wm * 64 + (q1) * 16 + r16) * BKB;            \
    ((int4*)&a1)[0] = *(const int4*)(p1_ + u0);                                   \
    ((int4*)&a1)[1] = *(const int4*)(p1_ + u1); }

#define MM1(am, bf, qq, jj)                                                       \
  acc[qq][jj] = __builtin_amdgcn_mfma_scale_f32_16x16x128_f8f6f4(                 \
      am, bf, acc[qq][jj], 0, 0, 0, 0x7F7F7F7F, 0, 0x7F7F7F7F);

#define MFMA8(B0, B1, B2, B3, q0, q1)                                             \
  MM1(a0, B0, q0, 0) MM1(a0, B1, q0, 1) MM1(a0, B2, q0, 2) MM1(a0, B3, q0, 3)    \
  MM1(a1, B0, q1, 0) MM1(a1, B1, q1, 1) MM1(a1, B2, q1, 2) MM1(a1, B3, q1, 3)

#define VMB(n) do { asm volatile("s_waitcnt vmcnt(" #n ")" ::: "memory");         \
    __builtin_amdgcn_s_barrier(); } while (0)

    f32x4 acc[4][4] = {};
    i32x8 a0, a1, be0, be1, be2, be3, bo0, bo1, bo2, bo3;

    // prologue: B(0) -> be, A(0) -> buf0
    BLOADS(be0, be1, be2, be3, 0u);
    STAGE_A(0, 0);

    const int NT = K / BKB;   // 16 (even)
    for (int t = 0; t < NT - 2; t += 2) {
        // even tile t (buf0, be); prefetch B(t+1), stage A(t+1)->buf1
        BLOADS(bo0, bo1, bo2, bo3, (uint32_t)(t + 1) * BKB);
        VMB(8);                       // A(t), be resident; bo stays in flight
        STAGE_A(1, t + 1);
        LDA2(0, 0, 1); MFMA8(be0, be1, be2, be3, 0, 1);
        LDA2(0, 2, 3); MFMA8(be0, be1, be2, be3, 2, 3);
        // odd tile t+1 (buf1, bo); prefetch B(t+2), stage A(t+2)->buf0
        BLOADS(be0, be1, be2, be3, (uint32_t)(t + 2) * BKB);
        VMB(8);
        STAGE_A(0, t + 2);
        LDA2(1, 0, 1); MFMA8(bo0, bo1, bo2, bo3, 0, 1);
        LDA2(1, 2, 3); MFMA8(bo0, bo1, bo2, bo3, 2, 3);
    }
    // final pair t = NT-2, NT-1
    BLOADS(bo0, bo1, bo2, bo3, (uint32_t)(NT - 1) * BKB);
    VMB(8);
    STAGE_A(1, NT - 1);
    LDA2(0, 0, 1); MFMA8(be0, be1, be2, be3, 0, 1);
    LDA2(0, 2, 3); MFMA8(be0, be1, be2, be3, 2, 3);
    VMB(0);                           // drain A(NT-1), bo
    LDA2(1, 0, 1); MFMA8(bo0, bo1, bo2, bo3, 0, 1);
    LDA2(1, 2, 3); MFMA8(bo0, bo1, bo2, bo3, 2, 3);

    // epilogue: scale, fp16-round, fp16 bias add, widen to f32
    const float sx = 448.f / fmaxf(scal[0], 1e-12f);
    const float sw = 448.f / fmaxf(scal[1], 1e-12f);
    const float inv = (1.f / sx) * (1.f / sw);

    #pragma unroll
    for (int mi = 0; mi < 4; ++mi) {
        #pragma unroll
        for (int nj = 0; nj < 4; ++nj) {
            int col = bn * BN + wn * 64 + nj * 16 + r16;
            __half hb = __float2half(bias[col]);
            #pragma unroll
            for (int r = 0; r < 4; ++r) {
                int row = bm * BM + wm * 64 + mi * 16 + hi * 4 + r;
                float v = acc[mi][nj][r] * inv;
                __half h = __hadd(__float2half(v), hb);
                C[(size_t)row * N + col] = __half2float(h);
            }
        }
    }
}

extern "C" void kernel_launch(void* const* d_in, const int* in_sizes, int n_in,
                              void* d_out, int out_size, void* d_ws, size_t ws_size,
                              hipStream_t stream) {
    const float* x    = (const float*)d_in[0];
    const float* w    = (const float*)d_in[1];
    const float* bias = (const float*)d_in[2];   // fp16 in reference -> f32 on device
    float* out = (float*)d_out;

    const int N = in_sizes[2];              // 8192
    const int K = in_sizes[1] / N;          // 2048
    const int M = in_sizes[0] / K;          // 16384

    uint8_t* ws = (uint8_t*)d_ws;
    float* scal = (float*)ws;               // [0]=amax_x, [1]=amax_w
    uint8_t* Aq = ws + 256;
    uint8_t* Bq = Aq + (size_t)M * K;

    hipMemsetAsync(scal, 0, 8, stream);

    const int axb = 2048, awb = 1024;
    amax2_kernel<<<axb + awb, 256, 0, stream>>>(x, (size_t)M * K / 4,
                                                w, (size_t)N * K / 4,
                                                scal, axb, awb);

    int qxb = (int)((size_t)M * K / 16 / 256);   // 8192
    int qwb = (int)((size_t)N * K / 16 / 256);   // 4096
    quant2_kernel<<<qxb + qwb, 256, 0, stream>>>(x, w, scal,
                                                 (uint32_t*)Aq, (uint32_t*)Bq, qxb);

    dim3 grid(N / BN, M / BM);   // 64 x 128, bn fast
    gemm_mxfp8_bs<<<grid, 256, 0, stream>>>(Aq, Bq, scal, bias, out, M, N, K);
}

// Round 15
// 446.332 us; speedup vs baseline: 1.5191x; 1.5191x over previous
//
#include <hip/hip_runtime.h>
#include <hip/hip_fp16.h>
#include <stdint.h>
#include <stddef.h>

typedef float f32x4 __attribute__((ext_vector_type(4)));
typedef int   i32x8 __attribute__((ext_vector_type(8)));

#define GLOBAL_AS __attribute__((address_space(1)))
#define LDS_AS    __attribute__((address_space(3)))

__device__ __forceinline__ void gload_lds16(const void* g, void* l) {
    __builtin_amdgcn_global_load_lds((const GLOBAL_AS void*)g,
                                     (LDS_AS void*)l, 16, 0, 0);
}

// ---------------- fused amax (x -> scal[0], w -> scal[1]) ----------------
__global__ void amax2_kernel(const float* __restrict__ x, size_t nx4,
                             const float* __restrict__ w, size_t nw4,
                             float* __restrict__ scal, int xblocks, int wblocks) {
    int b = blockIdx.x;
    const float4* p4; size_t n4; float* out; int nb; int bb;
    if (b < xblocks) { p4 = (const float4*)x; n4 = nx4; out = scal;     nb = xblocks; bb = b; }
    else             { p4 = (const float4*)w; n4 = nw4; out = scal + 1; nb = wblocks; bb = b - xblocks; }
    float m = 0.f;
    for (size_t i = (size_t)bb * blockDim.x + threadIdx.x; i < n4;
         i += (size_t)nb * blockDim.x) {
        float4 v = p4[i];
        m = fmaxf(m, fmaxf(fmaxf(fabsf(v.x), fabsf(v.y)),
                           fmaxf(fabsf(v.z), fabsf(v.w))));
    }
    #pragma unroll
    for (int off = 32; off > 0; off >>= 1)
        m = fmaxf(m, __shfl_down(m, off, 64));
    __shared__ float sm[4];
    int wid = threadIdx.x >> 6;
    if ((threadIdx.x & 63) == 0) sm[wid] = m;
    __syncthreads();
    if (threadIdx.x == 0) {
        m = fmaxf(fmaxf(sm[0], sm[1]), fmaxf(sm[2], sm[3]));
        atomicMax((unsigned int*)out, __float_as_uint(m));
    }
}

// ---------------- fused fp8 e4m3 quantization (16 elems/thread) ----------------
__global__ void quant2_kernel(const float* __restrict__ x, const float* __restrict__ w,
                              const float* __restrict__ scal,
                              uint32_t* __restrict__ qx, uint32_t* __restrict__ qw,
                              int xblocks) {
    int b = blockIdx.x;
    const float* src; uint32_t* dst; float sc; size_t i;
    if (b < xblocks) { src = x; dst = qx; sc = 448.f / fmaxf(scal[0], 1e-12f);
                       i = (size_t)b * blockDim.x + threadIdx.x; }
    else             { src = w; dst = qw; sc = 448.f / fmaxf(scal[1], 1e-12f);
                       i = (size_t)(b - xblocks) * blockDim.x + threadIdx.x; }
    const float4* s4 = (const float4*)src + i * 4;
    uint32_t r[4];
    #pragma unroll
    for (int j = 0; j < 4; ++j) {
        float4 v = s4[j];
        uint32_t u = __builtin_amdgcn_cvt_pk_fp8_f32(v.x * sc, v.y * sc, 0u, false);
        u = __builtin_amdgcn_cvt_pk_fp8_f32(v.z * sc, v.w * sc, u, true);
        r[j] = u;
    }
    uint4 out; out.x = r[0]; out.y = r[1]; out.z = r[2]; out.w = r[3];
    *(uint4*)(dst + i * 4) = out;
}

// ------- MX-fp8 GEMM (unit scales): C[M][N] = A[M][K] * B[N][K]^T -------
// r13 configuration, best measured (444.8 us total; GEMM 351 us, 1566 TF =
// the m97-structure MX-fp8 ceiling). All deep-pipeline/grid/B-stream variants
// measured worse: spills (r4/r5/r8), L2-feed-bound (r6), L2-thrash (r10),
// uncoalesced B fragment loads (r14).
#define BM 128
#define BN 128
#define BKB 128

__global__ __launch_bounds__(256) void gemm_mxfp8_kernel(
    const uint8_t* __restrict__ Aq,   // [M][K] fp8
    const uint8_t* __restrict__ Bq,   // [N][K] fp8
    const float* __restrict__ scal,   // {amax_x, amax_w}
    const float* __restrict__ bias,   // [N] f32 holding fp16-exact values
    float* __restrict__ C,            // [M][N] f32 (fp16-rounded values)
    int M, int N, int K)
{
    __shared__ __align__(16) uint8_t As[BM * BKB];   // 16 KB
    __shared__ __align__(16) uint8_t Bs[BN * BKB];   // 16 KB

    const int tid  = threadIdx.x;
    const int wid  = tid >> 6;
    const int lane = tid & 63;
    const int wm = wid >> 1, wn = wid & 1;   // 2x2 waves, 64x64 each
    const int bn = blockIdx.x, bm = blockIdx.y;
    const int r16 = lane & 15, hi = lane >> 4;

    // ---- staging addresses (pre-swizzled global source) ----
    const int srow  = wid * 8 + (lane >> 3);
    const int schunk = ((lane & 7) ^ (lane >> 3)) << 4;
    const uint8_t* Abase = Aq + (size_t)(bm * BM + srow) * K + schunk;
    const uint8_t* Bbase = Bq + (size_t)(bn * BN + srow) * K + schunk;

    // ---- fragment-read swizzle: row&7 == r16&7 for all mi ----
    const int swz = r16 & 7;
    const int u0 = ((hi * 2)     ^ swz) << 4;
    const int u1 = ((hi * 2 + 1) ^ swz) << 4;

    f32x4 acc[4][4] = {};

    for (int k0 = 0; k0 < K; k0 += BKB) {
        #pragma unroll
        for (int rho = 0; rho < 4; ++rho) {
            gload_lds16(Abase + (size_t)rho * 32 * K + k0,
                        As + rho * 4096 + wid * 1024);
            gload_lds16(Bbase + (size_t)rho * 32 * K + k0,
                        Bs + rho * 4096 + wid * 1024);
        }
        __syncthreads();

        i32x8 a[4], b[4];
        #pragma unroll
        for (int mi = 0; mi < 4; ++mi) {
            const uint8_t* pa = As + (wm * 64 + mi * 16 + r16) * BKB;
            int4 qa0 = *(const int4*)(pa + u0);
            int4 qa1 = *(const int4*)(pa + u1);
            a[mi] = (i32x8){qa0.x, qa0.y, qa0.z, qa0.w,
                            qa1.x, qa1.y, qa1.z, qa1.w};
            const uint8_t* pb = Bs + (wn * 64 + mi * 16 + r16) * BKB;
            int4 qb0 = *(const int4*)(pb + u0);
            int4 qb1 = *(const int4*)(pb + u1);
            b[mi] = (i32x8){qb0.x, qb0.y, qb0.z, qb0.w,
                            qb1.x, qb1.y, qb1.z, qb1.w};
        }

        #pragma unroll
        for (int mi = 0; mi < 4; ++mi)
            #pragma unroll
            for (int nj = 0; nj < 4; ++nj)
                acc[mi][nj] = __builtin_amdgcn_mfma_scale_f32_16x16x128_f8f6f4(
                    a[mi], b[nj], acc[mi][nj],
                    0, 0, 0, 0x7F7F7F7F, 0, 0x7F7F7F7F);
        __syncthreads();
    }

    // epilogue: scale, fp16-round, fp16 bias add, widen to f32
    const float sx = 448.f / fmaxf(scal[0], 1e-12f);
    const float sw = 448.f / fmaxf(scal[1], 1e-12f);
    const float inv = (1.f / sx) * (1.f / sw);

    #pragma unroll
    for (int mi = 0; mi < 4; ++mi) {
        #pragma unroll
        for (int nj = 0; nj < 4; ++nj) {
            int col = bn * BN + wn * 64 + nj * 16 + r16;
            __half hb = __float2half(bias[col]);
            #pragma unroll
            for (int r = 0; r < 4; ++r) {
                int row = bm * BM + wm * 64 + mi * 16 + hi * 4 + r;
                float v = acc[mi][nj][r] * inv;
                __half h = __hadd(__float2half(v), hb);
                C[(size_t)row * N + col] = __half2float(h);
            }
        }
    }
}

extern "C" void kernel_launch(void* const* d_in, const int* in_sizes, int n_in,
                              void* d_out, int out_size, void* d_ws, size_t ws_size,
                              hipStream_t stream) {
    const float* x    = (const float*)d_in[0];
    const float* w    = (const float*)d_in[1];
    const float* bias = (const float*)d_in[2];   // fp16 in reference -> f32 on device
    float* out = (float*)d_out;

    const int N = in_sizes[2];              // 8192
    const int K = in_sizes[1] / N;          // 2048
    const int M = in_sizes[0] / K;          // 16384

    uint8_t* ws = (uint8_t*)d_ws;
    float* scal = (float*)ws;               // [0]=amax_x, [1]=amax_w
    uint8_t* Aq = ws + 256;
    uint8_t* Bq = Aq + (size_t)M * K;

    hipMemsetAsync(scal, 0, 8, stream);

    const int axb = 2048, awb = 1024;
    amax2_kernel<<<axb + awb, 256, 0, stream>>>(x, (size_t)M * K / 4,
                                                w, (size_t)N * K / 4,
                                                scal, axb, awb);

    int qxb = (int)((size_t)M * K / 16 / 256);   // 8192
    int qwb = (int)((size_t)N * K / 16 / 256);   // 4096
    quant2_kernel<<<qxb + qwb, 256, 0, stream>>>(x, w, scal,
                                                 (uint32_t*)Aq, (uint32_t*)Bq, qxb);

    dim3 grid(N / BN, M / BM);   // 64 x 128, bn fast (r3-exact)
    gemm_mxfp8_kernel<<<grid, 256, 0, stream>>>(Aq, Bq, scal, bias, out, M, N, K);
}